// Round 6
// baseline (218.939 us; speedup 1.0000x reference)
//
#include <hip/hip_runtime.h>

typedef __attribute__((ext_vector_type(8))) short bf16x8;
typedef __attribute__((ext_vector_type(16))) float f32x16;

__device__ __forceinline__ unsigned short f2b(float f) {
  unsigned x = __builtin_bit_cast(unsigned, f);
  x += 0x7fffu + ((x >> 16) & 1u);   // round-to-nearest-even
  return (unsigned short)(x >> 16);
}

// global -> LDS DMA, 16 B per lane, LDS dest = wave-uniform base + lane*16
__device__ __forceinline__ void dma16(const unsigned short* g, unsigned short* l) {
  __builtin_amdgcn_global_load_lds(
      (const __attribute__((address_space(1))) unsigned int*)g,
      (__attribute__((address_space(3))) unsigned int*)l, 16, 0, 0);
}

// ---------------------------------------------------------------------------
// Kernel 0: W [768][384] fp32 -> Wt fragment-major bf16:
//             frag fid = ((kt*4 + s)*2 + h)*384 + n   (kt<12, s<4, h<2, n<384)
//             frag content (8 shorts): bf16(W[kt*64 + s*16 + h*8 + i][n])
//           Y [128][384] fp32 -> Ybf bf16 + y2[l] fp32
// ---------------------------------------------------------------------------
__global__ __launch_bounds__(256) void k_prep(const float* __restrict__ W,
                                              const float* __restrict__ Y,
                                              unsigned short* __restrict__ Wt,
                                              unsigned short* __restrict__ Ybf,
                                              float* __restrict__ y2) {
  int b = blockIdx.x;
  if (b < 144) {
    int fid = b * 256 + threadIdx.x;   // 36864 frags total
    int kt  = fid / 3072;
    int rem = fid - kt * 3072;
    int sh  = rem / 384;               // s*2 + h  (0..7)
    int n   = rem - sh * 384;
    const float* src = W + (size_t)(kt * 64 + sh * 8) * 384 + n;
    unsigned short o[8];
#pragma unroll
    for (int i = 0; i < 8; i++) o[i] = f2b(src[(size_t)i * 384]);
    uint4 p;
    p.x = (unsigned)o[0] | ((unsigned)o[1] << 16);
    p.y = (unsigned)o[2] | ((unsigned)o[3] << 16);
    p.z = (unsigned)o[4] | ((unsigned)o[5] << 16);
    p.w = (unsigned)o[6] | ((unsigned)o[7] << 16);
    *(uint4*)(Wt + (size_t)fid * 8) = p;
  } else {
    int t = threadIdx.x;
    for (int i = t; i < 12288; i += 256) {
      float4 v = ((const float4*)Y)[i];
      ushort4 o;
      o.x = f2b(v.x); o.y = f2b(v.y); o.z = f2b(v.z); o.w = f2b(v.w);
      ((ushort4*)Ybf)[i] = o;
    }
    if (t < 128) {
      const float4* row = (const float4*)(Y + (size_t)t * 384);
      float s = 0.f;
#pragma unroll
      for (int j = 0; j < 96; j++) {
        float4 v = row[j];
        s += v.x * v.x + v.y * v.y + v.z * v.z + v.w * v.w;
      }
      y2[t] = s;
    }
  }
}

// ---------------------------------------------------------------------------
// Fused kernel, round 6: 64-row blocks, 512 threads (8 waves), grid 512,
//   LDS ~70 KB -> 2 INDEPENDENT blocks/CU (m114 co-scheduling) combined with
//   R5's W-DMA + counted-vmcnt pipeline:
//     per K-step: [vmcnt(2)+lgkm(0); barrier] -> MFMA(t) -> pack A(t+1)
//                 -> [lgkm(0); barrier] -> DMA W(t+1) -> load A(t+2)
//   W single-buffered (48 KB frag-major, global_load_lds); A double-buffered.
//   GEMM2: sX (bf16 x) aliases dead GEMM1 buffers; B direct from L2 Ybf.
// ---------------------------------------------------------------------------
#define LDSA 72   // padded A row stride (64 + 8): zero conflicts (R0/R1/R3-R5)
#define LDSX 392  // sX row stride (384 + 8 pad)

__global__ __launch_bounds__(512, 4) void k_main(const float* __restrict__ cls,
                                                 const unsigned short* __restrict__ Wt,
                                                 const float* __restrict__ bias,
                                                 const unsigned short* __restrict__ Ybf,
                                                 const float* __restrict__ y2,
                                                 float* __restrict__ xout,
                                                 float* __restrict__ out) {
  // shorts: ab0 [0,4608) ab1 [4608,9216)  (A [64][72] each)
  //         wb  [9216,33792)              (W 3072 frags x 8)
  // sX [64][392] = 25088 shorts aliases ab0/ab1/wb-front after GEMM1.
  __shared__ __align__(16) unsigned short sm[33792];  // 67584 B
  __shared__ float rs[64][4];
  __shared__ float sF[64];
  __shared__ float sQ[64];

  unsigned short* wb = sm + 9216;

  const int tid = threadIdx.x;
  const int bm = blockIdx.x * 64;
  const int wave = tid >> 6, lane = tid & 63;
  const int r = lane & 31, h = lane >> 5;
  const int rg = wave & 1, cg = wave >> 1;  // GEMM1: rows rg*32, cols cg*96

  f32x16 acc[3];
#pragma unroll
  for (int j = 0; j < 3; j++)
#pragma unroll
    for (int e = 0; e < 16; e++) acc[j][e] = 0.f;

  // A staging: 1 chunk/thread (64 rows x 8 chunks of 8 floats)
  const int arow = tid >> 3, akc = tid & 7;
  const float* asrc = cls + (size_t)(bm + arow) * 768 + akc * 8;

  // ---- prologue: DMA W(0) (oldest in vmcnt queue), A(0)/A(1) loads, pack A(0)
#pragma unroll
  for (int i = 0; i < 6; i++) {
    int fb = (wave * 6 + i) * 64;
    dma16(Wt + (size_t)(fb + lane) * 8, wb + (size_t)fb * 8);
  }
  float4 rA[2][2];
  rA[0][0] = *(const float4*)(asrc);
  rA[0][1] = *(const float4*)(asrc + 4);
  rA[1][0] = *(const float4*)(asrc + 64);
  rA[1][1] = *(const float4*)(asrc + 68);
  {  // pack A(0) into ab0 (compiler inserts the vmcnt wait for rA[0])
    uint4 p;
    p.x = (unsigned)f2b(rA[0][0].x) | ((unsigned)f2b(rA[0][0].y) << 16);
    p.y = (unsigned)f2b(rA[0][0].z) | ((unsigned)f2b(rA[0][0].w) << 16);
    p.z = (unsigned)f2b(rA[0][1].x) | ((unsigned)f2b(rA[0][1].y) << 16);
    p.w = (unsigned)f2b(rA[0][1].z) | ((unsigned)f2b(rA[0][1].w) << 16);
    *(uint4*)(sm + arow * LDSA + akc * 8) = p;
  }

#pragma unroll
  for (int t = 0; t < 12; t++) {
    // entry wait: W(t)'s 6 DMAs complete (queue: [W(t)x6, A(t+1)x2] -> vmcnt(2));
    // A-pack of tile t already visible via lgkm(0). Raw barrier: no vmcnt drain.
    if (t < 11) asm volatile("s_waitcnt vmcnt(2) lgkmcnt(0)" ::: "memory");
    else        asm volatile("s_waitcnt vmcnt(0) lgkmcnt(0)" ::: "memory");
    __builtin_amdgcn_s_barrier();

    // MFMA tile t: A from ab[t&1], B from single W buffer (frag-major)
    {
      const unsigned short* abt = sm + (t & 1) * 4608;
#pragma unroll
      for (int s = 0; s < 4; s++) {
        bf16x8 a = *(const bf16x8*)(abt + (rg * 32 + r) * LDSA + s * 16 + h * 8);
        const unsigned short* wf = wb + (size_t)((s * 2 + h) * 384) * 8;
        bf16x8 b0 = *(const bf16x8*)(wf + (size_t)(cg * 96 + r) * 8);
        bf16x8 b1 = *(const bf16x8*)(wf + (size_t)(cg * 96 + 32 + r) * 8);
        bf16x8 b2 = *(const bf16x8*)(wf + (size_t)(cg * 96 + 64 + r) * 8);
        acc[0] = __builtin_amdgcn_mfma_f32_32x32x16_bf16(a, b0, acc[0], 0, 0, 0);
        acc[1] = __builtin_amdgcn_mfma_f32_32x32x16_bf16(a, b1, acc[1], 0, 0, 0);
        acc[2] = __builtin_amdgcn_mfma_f32_32x32x16_bf16(a, b2, acc[2], 0, 0, 0);
      }
    }

    // pack A(t+1) into the other A buffer (its readers finished at MFMA(t-1))
    if (t + 1 < 12) {
      uint4 p;
      p.x = (unsigned)f2b(rA[(t + 1) & 1][0].x) | ((unsigned)f2b(rA[(t + 1) & 1][0].y) << 16);
      p.y = (unsigned)f2b(rA[(t + 1) & 1][0].z) | ((unsigned)f2b(rA[(t + 1) & 1][0].w) << 16);
      p.z = (unsigned)f2b(rA[(t + 1) & 1][1].x) | ((unsigned)f2b(rA[(t + 1) & 1][1].y) << 16);
      p.w = (unsigned)f2b(rA[(t + 1) & 1][1].z) | ((unsigned)f2b(rA[(t + 1) & 1][1].w) << 16);
      *(uint4*)(sm + ((t + 1) & 1) * 4608 + arow * LDSA + akc * 8) = p;
    }

    // bottom barrier: all waves done reading W(t) + A-pack visible
    asm volatile("s_waitcnt lgkmcnt(0)" ::: "memory");
    __builtin_amdgcn_s_barrier();

    // refill the pipeline: W(t+1) DMA first (vmcnt order), then A(t+2) loads
    if (t + 1 < 12) {
      const unsigned short* wsrc = Wt + (size_t)(t + 1) * 3072 * 8;
#pragma unroll
      for (int i = 0; i < 6; i++) {
        int fb = (wave * 6 + i) * 64;
        dma16(wsrc + (size_t)(fb + lane) * 8, wb + (size_t)fb * 8);
      }
    }
    if (t + 2 < 12) {
      rA[t & 1][0] = *(const float4*)(asrc + (t + 2) * 64);
      rA[t & 1][1] = *(const float4*)(asrc + (t + 2) * 64 + 4);
    }
  }

  // ---- expmap0 epilogue: bias add + per-row ||.||^2 ----
  float bcol[3];
#pragma unroll
  for (int j = 0; j < 3; j++) bcol[j] = bias[cg * 96 + j * 32 + r];

#pragma unroll
  for (int reg = 0; reg < 16; reg++) {
    float s = 0.f;
#pragma unroll
    for (int j = 0; j < 3; j++) {
      float v = acc[j][reg] + bcol[j];
      acc[j][reg] = v;
      s += v * v;
    }
    s += __shfl_xor(s, 1);
    s += __shfl_xor(s, 2);
    s += __shfl_xor(s, 4);
    s += __shfl_xor(s, 8);
    s += __shfl_xor(s, 16);
    if (r == 0) {
      int rowl = rg * 32 + (reg & 3) + 8 * (reg >> 2) + 4 * h;
      rs[rowl][cg] = s;
    }
  }
  asm volatile("s_waitcnt lgkmcnt(0)" ::: "memory");
  __builtin_amdgcn_s_barrier();
  if (tid < 64) {
    float n2 = rs[tid][0] + rs[tid][1] + rs[tid][2] + rs[tid][3];
    float n = fmaxf(sqrtf(n2), 1e-15f);
    float f = tanhf(n) / n;
    sF[tid] = f;
    sQ[tid] = n2 * f * f;  // ||x||^2 in fp32 (clip-sensitivity)
  }
  asm volatile("s_waitcnt lgkmcnt(0)" ::: "memory");
  __builtin_amdgcn_s_barrier();

  // scale -> write x to global AND bf16-x into LDS (aliases dead buffers)
#pragma unroll
  for (int reg = 0; reg < 16; reg++) {
    int rowl = rg * 32 + (reg & 3) + 8 * (reg >> 2) + 4 * h;
    float f = sF[rowl];
#pragma unroll
    for (int j = 0; j < 3; j++) {
      float v = acc[j][reg] * f;
      int col = cg * 96 + j * 32 + r;
      xout[(size_t)(bm + rowl) * 384 + col] = v;
      sm[rowl * LDSX + col] = f2b(v);
    }
  }
  asm volatile("s_waitcnt lgkmcnt(0)" ::: "memory");
  __builtin_amdgcn_s_barrier();

  // ---- GEMM2: logits = -poincare_dist(x, Y); B direct from L2 Ybf ----
  const int rt = (wave & 1) * 32, ct = (wave >> 1) * 32;
  f32x16 acc2;
#pragma unroll
  for (int e = 0; e < 16; e++) acc2[e] = 0.f;

#pragma unroll
  for (int cc = 0; cc < 6; cc++) {
#pragma unroll
    for (int sub = 0; sub < 4; sub++) {
      const int kk = cc * 64 + sub * 16 + h * 8;
      bf16x8 a = *(const bf16x8*)(sm + (rt + r) * LDSX + kk);
      bf16x8 b = *(const bf16x8*)(Ybf + (size_t)(ct + r) * 384 + kk);
      acc2 = __builtin_amdgcn_mfma_f32_32x32x16_bf16(a, b, acc2, 0, 0, 0);
    }
  }

  const float CLIP = 0.9999800001f;  // (1 - 1e-5)^2
  float yc = y2[ct + r];
#pragma unroll
  for (int reg = 0; reg < 16; reg++) {
    int rowl = rt + (reg & 3) + 8 * (reg >> 2) + 4 * h;
    float xr = sQ[rowl];
    float xy = acc2[reg];
    float sq = xr + yc - 2.f * xy;
    float den = 1.f - 2.f * xy + xr * yc;
    float ratio = fminf(fmaxf(sq / den, 0.f), CLIP);
    float s = sqrtf(ratio);
    float dist = logf((1.f + s) / (1.f - s));  // 2*atanh(s)
    out[(size_t)(bm + rowl) * 128 + ct + r] = -dist;
  }
}

// ---------------------------------------------------------------------------
extern "C" void kernel_launch(void* const* d_in, const int* in_sizes, int n_in,
                              void* d_out, int out_size, void* d_ws, size_t ws_size,
                              hipStream_t stream) {
  const float* cls  = (const float*)d_in[0];  // [32768][768] fp32
  const float* W    = (const float*)d_in[1];  // [768][384] fp32
  const float* bias = (const float*)d_in[2];  // [384] fp32
  const float* Y    = (const float*)d_in[3];  // [128][384] fp32

  float* out_logits = (float*)d_out;                    // [32768][128] fp32
  float* out_x = out_logits + (size_t)32768 * 128;      // [32768][384] fp32

  float* x2 = (float*)d_ws;                           // (unused)
  float* y2 = x2 + 32768;                             // 128 fp32
  unsigned short* Wt = (unsigned short*)(y2 + 128);   // 36864 frags x 16 B
  unsigned short* Ybf = Wt + (size_t)384 * 768;       // [128][384] bf16

  k_prep<<<145, 256, 0, stream>>>(W, Y, Wt, Ybf, y2);
  k_main<<<512, 512, 0, stream>>>(cls, Wt, bias, Ybf, y2, out_x, out_logits);
}